// Round 11
// baseline (70.613 us; speedup 1.0000x reference)
//
#include <hip/hip_runtime.h>

// PolynomialRegression via bf16 MFMA — SINGLE LAUNCH, no workspace:
//   y[b][o] = bias_o + sum_i x[b][i] * ( (U_o x[b])_i + W1[o][i] )
// 64-row x 1-o blocks; x-tile staged fp32->bf16 in LDS (1 barrier).
// Uniform fully-unrolled 9-chunk loop (balanced pairs {w,7-w} -> 72
// MFMA/wave); B-frags packed IN-LOOP from W (fp32, L2-hot): 2 dwordx4 +
// 4 v_perm per frag, all 36 loads pipelined by the unroll. Triangle mask
// only at t==0 and t==rem, pattern (q8+e<ln)/(q8+e<ln+16) — wave-invariant.
// Fused fp32 quadratic-form epilogue, x from LDS, direct stores.

#define DD 256
#define NF 33153
#define TPB 256
#define ASTRIDE 264   // bf16 elems; 528 B row stride -> 2-way LDS alias (free)

typedef __attribute__((ext_vector_type(8))) short short8;
typedef __attribute__((ext_vector_type(4))) float floatx4;
typedef __attribute__((ext_vector_type(4), aligned(4))) float float4a;

union S8U { unsigned u[4]; short8 s; };

__device__ inline unsigned pack2(float lo, float hi) {   // 2xfp32 -> bf16x2, half-up
    unsigned a = __builtin_bit_cast(unsigned, hi) + 0x8000u;
    unsigned b = __builtin_bit_cast(unsigned, lo) + 0x8000u;
    return __builtin_amdgcn_perm(a, b, 0x07060302u);
}

__global__ __launch_bounds__(TPB, 3)
void PolynomialRegression_75385265979710_kernel(const float* __restrict__ x,
                                                const float* __restrict__ W,
                                                float* __restrict__ out) {
    __shared__ __align__(16) unsigned short As[64 * ASTRIDE];  // 33792 B
    __shared__ float red[4 * 64];

    const int tid  = threadIdx.x;
    const int lane = tid & 63, wave = tid >> 6;
    const int ln   = lane & 15, quad = lane >> 4;
    const int q8   = quad * 8;
    const int rowbase = blockIdx.x * 64;
    const int o  = blockIdx.y;
    const int g1 = wave, g2 = 7 - wave;
    const int rem = 8 - wave;            // chunks in group g1

    // --- stage x-tile (64 x 256) fp32 -> bf16 into padded LDS ---
#pragma unroll
    for (int it = 0; it < 8; ++it) {
        int idx = it * 2048 + tid * 8;
        int r = idx >> 8, c = idx & 255;
        const float* src = &x[(rowbase + r) * DD + c];
        float4a v0 = *(const float4a*)src;
        float4a v1 = *(const float4a*)(src + 4);
        S8U p;
        p.u[0] = pack2(v0.x, v0.y); p.u[1] = pack2(v0.z, v0.w);
        p.u[2] = pack2(v1.x, v1.y); p.u[3] = pack2(v1.z, v1.w);
        *(short8*)&As[r * ASTRIDE + c] = p.s;
    }

    // hoisted epilogue constants (latency hides under K-loop)
    int iRow[4];
    float w1v[4];
#pragma unroll
    for (int nt = 0; nt < 4; ++nt) {
        int g = (nt < 2) ? g1 : g2;
        iRow[nt] = g * 32 + (nt & 1) * 16 + ln;
        w1v[nt]  = W[o * NF + 1 + iRow[nt]];
    }
    const float bias = W[o * NF];

    // per-group W2 row bases (element (i,i) is at base + i)
    //   rowPtr(i) = o*NF + 257 + i*255 - i(i-1)/2, frag addr = rowPtr + kc*32 + q8
    int rb[2][2];   // [group 0=g1,1=g2][sub 0=+ln,1=+16+ln]
#pragma unroll
    for (int gg = 0; gg < 2; ++gg) {
        int g = gg ? g2 : g1;
        int i0 = g * 32 + ln, i1 = i0 + 16;
        rb[gg][0] = o * NF + 257 + i0 * 255 - ((i0 * (i0 - 1)) >> 1) + q8;
        rb[gg][1] = o * NF + 257 + i1 * 255 - ((i1 * (i1 - 1)) >> 1) + q8;
    }

    __syncthreads();

    floatx4 acc[4][4];   // [m_tile][n_tile: 0,1 = group g1; 2,3 = group g2]
#pragma unroll
    for (int mt = 0; mt < 4; ++mt)
#pragma unroll
        for (int nt = 0; nt < 4; ++nt) acc[mt][nt] = (floatx4)0.f;

    // --- uniform 9-chunk loop, fully unrolled ---
#pragma unroll
    for (int t = 0; t < 9; ++t) {
        const bool first  = (t < rem);                     // wave-uniform
        const int  gg     = first ? 0 : 1;
        const int  kc     = first ? (g1 + t) : (g2 + (t - rem));
        const bool masked = (t == 0) || (t == rem);        // diagonal chunk

        const float* p0 = &W[rb[gg][0] + kc * 32];
        const float* p1 = &W[rb[gg][1] + kc * 32];
        float4a w00 = *(const float4a*)p0, w01 = *(const float4a*)(p0 + 4);
        float4a w10 = *(const float4a*)p1, w11 = *(const float4a*)(p1 + 4);
        float f0[8] = {w00.x, w00.y, w00.z, w00.w, w01.x, w01.y, w01.z, w01.w};
        float f1[8] = {w10.x, w10.y, w10.z, w10.w, w11.x, w11.y, w11.z, w11.w};
        if (masked) {   // zero j<i: pattern independent of wave/group/o
#pragma unroll
            for (int e = 0; e < 8; ++e) {
                if (q8 + e < ln)      f0[e] = 0.f;
                if (q8 + e < ln + 16) f1[e] = 0.f;
            }
        }
        S8U pb0, pb1;
        pb0.u[0] = pack2(f0[0], f0[1]); pb0.u[1] = pack2(f0[2], f0[3]);
        pb0.u[2] = pack2(f0[4], f0[5]); pb0.u[3] = pack2(f0[6], f0[7]);
        pb1.u[0] = pack2(f1[0], f1[1]); pb1.u[1] = pack2(f1[2], f1[3]);
        pb1.u[2] = pack2(f1[4], f1[5]); pb1.u[3] = pack2(f1[6], f1[7]);
        short8 b0 = pb0.s, b1 = pb1.s;

        short8 a[4];
#pragma unroll
        for (int mt = 0; mt < 4; ++mt)
            a[mt] = *(const short8*)&As[(mt * 16 + ln) * ASTRIDE + kc * 32 + q8];

        if (first) {
#pragma unroll
            for (int mt = 0; mt < 4; ++mt) {
                acc[mt][0] = __builtin_amdgcn_mfma_f32_16x16x32_bf16(a[mt], b0, acc[mt][0], 0, 0, 0);
                acc[mt][1] = __builtin_amdgcn_mfma_f32_16x16x32_bf16(a[mt], b1, acc[mt][1], 0, 0, 0);
            }
        } else {
#pragma unroll
            for (int mt = 0; mt < 4; ++mt) {
                acc[mt][2] = __builtin_amdgcn_mfma_f32_16x16x32_bf16(a[mt], b0, acc[mt][2], 0, 0, 0);
                acc[mt][3] = __builtin_amdgcn_mfma_f32_16x16x32_bf16(a[mt], b1, acc[mt][3], 0, 0, 0);
            }
        }
    }

    // --- epilogue: y_part[m] = sum_{i in wave's set} x[m][i]*(T[m][i]+W1[o][i])
#pragma unroll
    for (int mt = 0; mt < 4; ++mt) {
#pragma unroll
        for (int r = 0; r < 4; ++r) {
            const int m = mt * 16 + quad * 4 + r;   // C/D: row=quad*4+reg, col=ln
            float p = 0.f;
#pragma unroll
            for (int nt = 0; nt < 4; ++nt) {
                unsigned u = As[m * ASTRIDE + iRow[nt]];
                float xv = __builtin_bit_cast(float, u << 16);
                p = fmaf(xv, acc[mt][nt][r] + w1v[nt], p);
            }
            p += __shfl_xor(p, 1);
            p += __shfl_xor(p, 2);
            p += __shfl_xor(p, 4);
            p += __shfl_xor(p, 8);
            if (ln == 0) red[wave * 64 + m] = p;
        }
    }
    __syncthreads();

    if (tid < 64) {
        float s = red[tid] + red[64 + tid] + red[128 + tid] + red[192 + tid]
                + bias;
        out[(rowbase + tid) * 10 + o] = s;
    }
}

extern "C" void kernel_launch(void* const* d_in, const int* in_sizes, int n_in,
                              void* d_out, int out_size, void* d_ws, size_t ws_size,
                              hipStream_t stream) {
    const float* x = (const float*)d_in[0];   // (4096, 256)
    const float* W = (const float*)d_in[1];   // (10, 33153)
    float* out = (float*)d_out;               // (4096, 10)

    dim3 grid(4096 / 64, 10);
    PolynomialRegression_75385265979710_kernel<<<grid, TPB, 0, stream>>>(x, W, out);
}